// Round 3
// baseline (2090.313 us; speedup 1.0000x reference)
//
#include <hip/hip_runtime.h>
#include <stdint.h>

#define B_ 2
#define S_ 4096
#define D_ 768
#define H_ 12
#define F_ 3072
#define DK_ 64

typedef __bf16 bf16x8 __attribute__((ext_vector_type(8)));
typedef float floatx4 __attribute__((ext_vector_type(4)));

__device__ __forceinline__ float bf2f(unsigned short u) {
  unsigned int x = ((unsigned int)u) << 16;
  return __builtin_bit_cast(float, x);
}
__device__ __forceinline__ unsigned short f2bf(float f) {
  unsigned int x = __builtin_bit_cast(unsigned int, f);
  x += 0x7FFFu + ((x >> 16) & 1u);
  return (unsigned short)(x >> 16);
}

// ---------------- weight transpose + cvt: w[K][N] f32 -> wt[N][K] bf16 ----------------
__global__ __launch_bounds__(256) void wtrans(const float* __restrict__ w,
                                              unsigned short* __restrict__ wt,
                                              int K, int N) {
  __shared__ float tile[32][33];
  const int n0 = blockIdx.x * 32, k0 = blockIdx.y * 32;
  const int tx = threadIdx.x & 31, ty8 = threadIdx.x >> 5;  // ty8: 0..7
#pragma unroll
  for (int r = 0; r < 4; r++)
    tile[ty8 + r * 8][tx] = w[(size_t)(k0 + ty8 + r * 8) * N + n0 + tx];
  __syncthreads();
#pragma unroll
  for (int r = 0; r < 4; r++)
    wt[(size_t)(n0 + ty8 + r * 8) * K + k0 + tx] = f2bf(tile[tx][ty8 + r * 8]);
}

// ---------------- GEMM: out[M][N] = A[M][K] @ Bt[N][K]^T + bias (+resid) (+relu) ----------------
// 128x128 block tile, BK=32, 4 waves each 64x64 (4x4 mfma_f32_16x16x32_bf16).
template <bool A_F32, bool RELU, bool RESID, bool OUT_BF16>
__global__ __launch_bounds__(256, 2) void gemm_bt(
    const void* __restrict__ Av, const unsigned short* __restrict__ Bt,
    const float* __restrict__ bias, const float* __restrict__ resid,
    void* __restrict__ outv, int M, int N, int K) {
  __shared__ __align__(16) unsigned short As[128][40];
  __shared__ __align__(16) unsigned short Bs[128][40];
  const int t = threadIdx.x;
  const int lane = t & 63, wave = t >> 6;
  const int m0 = blockIdx.y * 128, n0 = blockIdx.x * 128;
  const int wm = (wave >> 1) * 64, wn = (wave & 1) * 64;
  const int rl = lane & 15, kl = (lane >> 4) * 8;
  const int srow = t >> 1, scol = (t & 1) * 16;

  floatx4 zf = {0.f, 0.f, 0.f, 0.f};
  floatx4 acc[4][4];
#pragma unroll
  for (int i = 0; i < 4; i++)
#pragma unroll
    for (int j = 0; j < 4; j++) acc[i][j] = zf;

  for (int k0 = 0; k0 < K; k0 += 32) {
    if (A_F32) {
      const float* ap = (const float*)Av + (size_t)(m0 + srow) * K + k0 + scol;
      float4 f[4];
#pragma unroll
      for (int q = 0; q < 4; q++) f[q] = ((const float4*)ap)[q];
      const float* fv = (const float*)&f[0];
      unsigned int w[8];
#pragma unroll
      for (int e = 0; e < 8; e++)
        w[e] = (unsigned int)f2bf(fv[2 * e]) | ((unsigned int)f2bf(fv[2 * e + 1]) << 16);
      *(uint4*)&As[srow][scol] = make_uint4(w[0], w[1], w[2], w[3]);
      *(uint4*)&As[srow][scol + 8] = make_uint4(w[4], w[5], w[6], w[7]);
    } else {
      const uint4* ap = (const uint4*)((const unsigned short*)Av + (size_t)(m0 + srow) * K + k0 + scol);
      *(uint4*)&As[srow][scol] = ap[0];
      *(uint4*)&As[srow][scol + 8] = ap[1];
    }
    {
      const uint4* bp = (const uint4*)(Bt + (size_t)(n0 + srow) * K + k0 + scol);
      *(uint4*)&Bs[srow][scol] = bp[0];
      *(uint4*)&Bs[srow][scol + 8] = bp[1];
    }
    __syncthreads();
    bf16x8 af[4], bff[4];
#pragma unroll
    for (int i = 0; i < 4; i++)
      af[i] = __builtin_bit_cast(bf16x8, *(const uint4*)&As[wm + i * 16 + rl][kl]);
#pragma unroll
    for (int j = 0; j < 4; j++)
      bff[j] = __builtin_bit_cast(bf16x8, *(const uint4*)&Bs[wn + j * 16 + rl][kl]);
#pragma unroll
    for (int i = 0; i < 4; i++)
#pragma unroll
      for (int j = 0; j < 4; j++)
        acc[i][j] = __builtin_amdgcn_mfma_f32_16x16x32_bf16(af[i], bff[j], acc[i][j], 0, 0, 0);
    __syncthreads();
  }

  const int r0 = (lane >> 4) * 4;
#pragma unroll
  for (int i = 0; i < 4; i++) {
#pragma unroll
    for (int j = 0; j < 4; j++) {
      const int col = n0 + wn + j * 16 + rl;
      const float bv = bias[col];
#pragma unroll
      for (int r = 0; r < 4; r++) {
        const int row = m0 + wm + i * 16 + r0 + r;
        float v = acc[i][j][r] + bv;
        if (RESID) v += resid[(size_t)row * N + col];
        if (RELU) v = v > 0.f ? v : 0.f;
        if (OUT_BF16)
          ((unsigned short*)outv)[(size_t)row * N + col] = f2bf(v);
        else
          ((float*)outv)[(size_t)row * N + col] = v;
      }
    }
  }
}

// ---------------- flash attention, f32 compute, bf16 storage ----------------
// block: 256 threads, one (b,h, 128-row q tile); kv tiles of 64.
// thread (ty=t>>4, tx=t&15): owns q rows ty*8..+7, kv cols tx*4..+3 (scores)
// and d cols tx*4..+3 (output).
__global__ __launch_bounds__(256, 2) void flash_attn(
    const unsigned short* __restrict__ qg, const unsigned short* __restrict__ kg,
    const unsigned short* __restrict__ vg, const int* __restrict__ maskg,
    unsigned short* __restrict__ ctx) {
  __shared__ __align__(16) unsigned short Qt[64][136];  // [d][qrow]
  __shared__ __align__(16) unsigned short Kt[64][72];   // [d][kvrow]
  __shared__ __align__(16) unsigned short Vs[64][72];   // [kvrow][d]
  __shared__ __align__(16) unsigned short Pt[64][136];  // [kvrow][qrow]

  const int t = threadIdx.x;
  const int qb = blockIdx.x, h = blockIdx.y, b = blockIdx.z;
  const int ty = t >> 4, tx = t & 15;
  const unsigned short* qp = qg + ((size_t)(b * S_ + qb * 128)) * D_ + h * DK_;
  const unsigned short* kp = kg + (size_t)b * S_ * D_ + h * DK_;
  const unsigned short* vp = vg + (size_t)b * S_ * D_ + h * DK_;
  const int* mp = maskg + (size_t)b * S_;

  // stage Q transposed (once)
#pragma unroll
  for (int cc = 0; cc < 4; cc++) {
    int c = cc * 256 + t;
    int row = c >> 3, d0 = (c & 7) * 8;
    union { uint4 u; unsigned short e[8]; } u;
    u.u = *(const uint4*)(qp + (size_t)row * D_ + d0);
#pragma unroll
    for (int ee = 0; ee < 8; ee++) Qt[d0 + ee][row] = u.e[ee];
  }

  float O[8][4];
  float m_[8], l_[8];
#pragma unroll
  for (int i = 0; i < 8; i++) {
    m_[i] = -1e30f;
    l_[i] = 0.f;
#pragma unroll
    for (int j = 0; j < 4; j++) O[i][j] = 0.f;
  }

  for (int kt = 0; kt < S_ / 64; kt++) {
    const int kv0 = kt * 64;
    __syncthreads();  // protects Qt (iter 0) and Kt/Vs/Pt from previous iter reads
#pragma unroll
    for (int cc = 0; cc < 2; cc++) {
      int c = cc * 256 + t;
      int row = c >> 3, d0 = (c & 7) * 8;
      union { uint4 u; unsigned short e[8]; } uk;
      uk.u = *(const uint4*)(kp + (size_t)(kv0 + row) * D_ + d0);
#pragma unroll
      for (int ee = 0; ee < 8; ee++) Kt[d0 + ee][row] = uk.e[ee];
      *(uint4*)&Vs[row][d0] = *(const uint4*)(vp + (size_t)(kv0 + row) * D_ + d0);
    }
    __syncthreads();

    // scores S[i][j] = sum_d Q[qr][d] * K[kv][d]
    float S[8][4];
#pragma unroll
    for (int i = 0; i < 8; i++)
#pragma unroll
      for (int j = 0; j < 4; j++) S[i][j] = 0.f;

    for (int d = 0; d < 64; d++) {
      union { uint4 u; unsigned short e[8]; } qv;
      qv.u = *(const uint4*)&Qt[d][ty * 8];
      union { uint2 u; unsigned short e[4]; } kv;
      kv.u = *(const uint2*)&Kt[d][tx * 4];
      float qf[8], kf[4];
#pragma unroll
      for (int i = 0; i < 8; i++) qf[i] = bf2f(qv.e[i]);
#pragma unroll
      for (int j = 0; j < 4; j++) kf[j] = bf2f(kv.e[j]);
#pragma unroll
      for (int i = 0; i < 8; i++)
#pragma unroll
        for (int j = 0; j < 4; j++) S[i][j] = fmaf(qf[i], kf[j], S[i][j]);
    }

    int mv[4];
#pragma unroll
    for (int j = 0; j < 4; j++) mv[j] = mp[kv0 + tx * 4 + j];
#pragma unroll
    for (int i = 0; i < 8; i++)
#pragma unroll
      for (int j = 0; j < 4; j++)
        S[i][j] = mv[j] ? S[i][j] * 0.125f : -1e30f;

    // online softmax; row group = 16 lanes (xor masks 1,2,4,8 stay in group)
#pragma unroll
    for (int i = 0; i < 8; i++) {
      float rmax = fmaxf(fmaxf(S[i][0], S[i][1]), fmaxf(S[i][2], S[i][3]));
#pragma unroll
      for (int off = 1; off < 16; off <<= 1) rmax = fmaxf(rmax, __shfl_xor(rmax, off, 64));
      const float mn = fmaxf(m_[i], rmax);
      const float corr = exp2f((m_[i] - mn) * 1.44269504088896f);
      m_[i] = mn;
      float rs = 0.f;
#pragma unroll
      for (int j = 0; j < 4; j++) {
        S[i][j] = exp2f((S[i][j] - mn) * 1.44269504088896f);
        rs += S[i][j];
      }
#pragma unroll
      for (int off = 1; off < 16; off <<= 1) rs += __shfl_xor(rs, off, 64);
      l_[i] = l_[i] * corr + rs;
#pragma unroll
      for (int j = 0; j < 4; j++) O[i][j] *= corr;
    }

    // write P transposed: Pt[kv][qrow]
#pragma unroll
    for (int j = 0; j < 4; j++) {
      union { uint4 u; unsigned short e[8]; } pe;
#pragma unroll
      for (int i = 0; i < 8; i++) pe.e[i] = f2bf(S[i][j]);
      *(uint4*)&Pt[tx * 4 + j][ty * 8] = pe.u;
    }
    __syncthreads();

    // O[i][jd] += sum_j2 P[qr][j2] * V[j2][d]
    for (int j2 = 0; j2 < 64; j2++) {
      union { uint4 u; unsigned short e[8]; } pv;
      pv.u = *(const uint4*)&Pt[j2][ty * 8];
      union { uint2 u; unsigned short e[4]; } vv;
      vv.u = *(const uint2*)&Vs[j2][tx * 4];
      float pf[8], vf[4];
#pragma unroll
      for (int i = 0; i < 8; i++) pf[i] = bf2f(pv.e[i]);
#pragma unroll
      for (int j = 0; j < 4; j++) vf[j] = bf2f(vv.e[j]);
#pragma unroll
      for (int i = 0; i < 8; i++)
#pragma unroll
        for (int j = 0; j < 4; j++) O[i][j] = fmaf(pf[i], vf[j], O[i][j]);
    }
  }

#pragma unroll
  for (int i = 0; i < 8; i++) {
    const float inv = 1.f / l_[i];
    union { uint2 u; unsigned short e[4]; } oe;
#pragma unroll
    for (int j = 0; j < 4; j++) oe.e[j] = f2bf(O[i][j] * inv);
    const size_t row = (size_t)(b * S_ + qb * 128 + ty * 8 + i);
    *(uint2*)&ctx[row * D_ + h * DK_ + tx * 4] = oe.u;
  }
}

// ---------------- LayerNorm over rows of 768 ----------------
__global__ __launch_bounds__(256) void ln_kernel(const float* __restrict__ x,
                                                 const float* __restrict__ g,
                                                 const float* __restrict__ be,
                                                 float* __restrict__ out) {
  __shared__ float red[4];
  const int t = threadIdx.x, lane = t & 63, wave = t >> 6;
  const size_t row = blockIdx.x;
  const float* xr = x + row * D_;
  float v0 = xr[t], v1 = xr[t + 256], v2 = xr[t + 512];
  float s = v0 + v1 + v2;
#pragma unroll
  for (int off = 32; off; off >>= 1) s += __shfl_xor(s, off, 64);
  if (lane == 0) red[wave] = s;
  __syncthreads();
  const float mu = (red[0] + red[1] + red[2] + red[3]) * (1.f / 768.f);
  __syncthreads();
  const float d0 = v0 - mu, d1 = v1 - mu, d2 = v2 - mu;
  float vs = d0 * d0 + d1 * d1 + d2 * d2;
#pragma unroll
  for (int off = 32; off; off >>= 1) vs += __shfl_xor(vs, off, 64);
  if (lane == 0) red[wave] = vs;
  __syncthreads();
  const float rs = rsqrtf((red[0] + red[1] + red[2] + red[3]) * (1.f / 768.f) + 1e-6f);
  float* orow = out + row * D_;
  orow[t] = d0 * rs * g[t] + be[t];
  orow[t + 256] = d1 * rs * g[t + 256] + be[t + 256];
  orow[t + 512] = d2 * rs * g[t + 512] + be[t + 512];
}

// ---------------- host launcher ----------------
extern "C" void kernel_launch(void* const* d_in, const int* in_sizes, int n_in,
                              void* d_out, int out_size, void* d_ws, size_t ws_size,
                              hipStream_t stream) {
  const float* xq = (const float*)d_in[0];
  const float* xk = (const float*)d_in[1];
  const float* xv = (const float*)d_in[2];
  const int* mask = (const int*)d_in[3];
  const float* wq = (const float*)d_in[4];
  const float* bq = (const float*)d_in[5];
  const float* wk = (const float*)d_in[6];
  const float* bk = (const float*)d_in[7];
  const float* wv = (const float*)d_in[8];
  const float* bv = (const float*)d_in[9];
  const float* wo = (const float*)d_in[10];
  const float* bo = (const float*)d_in[11];
  const float* w1 = (const float*)d_in[12];
  const float* b1 = (const float*)d_in[13];
  const float* w2 = (const float*)d_in[14];
  const float* b2 = (const float*)d_in[15];
  const float* g1 = (const float*)d_in[16];
  const float* be1 = (const float*)d_in[17];
  const float* g2 = (const float*)d_in[18];
  const float* be2 = (const float*)d_in[19];
  float* out = (float*)d_out;
  char* ws = (char*)d_ws;

  // workspace layout (bytes)
  unsigned short* WQT = (unsigned short*)(ws + 0);          // 768*768*2
  unsigned short* WKT = (unsigned short*)(ws + 1179648);
  unsigned short* WVT = (unsigned short*)(ws + 2359296);
  unsigned short* WOT = (unsigned short*)(ws + 3538944);
  unsigned short* W1T = (unsigned short*)(ws + 4718592);    // [3072][768]
  unsigned short* W2T = (unsigned short*)(ws + 9437184);    // [768][3072]
  unsigned short* QB = (unsigned short*)(ws + 14155776);    // 8192*768 bf16
  unsigned short* KB = (unsigned short*)(ws + 26738688);
  unsigned short* VB = (unsigned short*)(ws + 39321600);
  unsigned short* CTXB = (unsigned short*)(ws + 51904512);
  float* X1PRE = (float*)(ws + 64487424);                   // 8192*768 f32
  float* X1F = (float*)(ws + 89653248);                     // 8192*768 f32
  unsigned short* HB = (unsigned short*)(ws + 14155776);    // alias: q/k/v/ctx dead by FFN1
  float* X2PRE = (float*)(ws + 64487424);                   // alias: x1pre dead after LN1

  // weight transpose + cvt
  wtrans<<<dim3(24, 24), 256, 0, stream>>>(wq, WQT, 768, 768);
  wtrans<<<dim3(24, 24), 256, 0, stream>>>(wk, WKT, 768, 768);
  wtrans<<<dim3(24, 24), 256, 0, stream>>>(wv, WVT, 768, 768);
  wtrans<<<dim3(24, 24), 256, 0, stream>>>(wo, WOT, 768, 768);
  wtrans<<<dim3(96, 24), 256, 0, stream>>>(w1, W1T, 768, 3072);
  wtrans<<<dim3(24, 96), 256, 0, stream>>>(w2, W2T, 3072, 768);

  // QKV projections (A f32 -> bf16 staged), out bf16
  gemm_bt<true, false, false, true><<<dim3(6, 64), 256, 0, stream>>>(xq, WQT, bq, nullptr, QB, 8192, 768, 768);
  gemm_bt<true, false, false, true><<<dim3(6, 64), 256, 0, stream>>>(xk, WKT, bk, nullptr, KB, 8192, 768, 768);
  gemm_bt<true, false, false, true><<<dim3(6, 64), 256, 0, stream>>>(xv, WVT, bv, nullptr, VB, 8192, 768, 768);

  // flash attention -> ctx bf16
  flash_attn<<<dim3(32, H_, B_), 256, 0, stream>>>(QB, KB, VB, mask, CTXB);

  // attn output projection + residual(inputs_q) -> x1pre f32
  gemm_bt<false, false, true, false><<<dim3(6, 64), 256, 0, stream>>>(CTXB, WOT, bo, xq, X1PRE, 8192, 768, 768);

  // LN1
  ln_kernel<<<8192, 256, 0, stream>>>(X1PRE, g1, be1, X1F);

  // FFN1: x1 @ w1 + b1, relu -> h bf16
  gemm_bt<true, true, false, true><<<dim3(24, 64), 256, 0, stream>>>(X1F, W1T, b1, nullptr, HB, 8192, 3072, 768);

  // FFN2: h @ w2 + b2 + x1 -> x2pre f32
  gemm_bt<false, false, true, false><<<dim3(6, 64), 256, 0, stream>>>(HB, W2T, b2, X1F, X2PRE, 8192, 768, 3072);

  // LN2 -> out
  ln_kernel<<<8192, 256, 0, stream>>>(X2PRE, g2, be2, out);
}

// Round 4
// 805.744 us; speedup vs baseline: 2.5943x; 2.5943x over previous
//
#include <hip/hip_runtime.h>
#include <stdint.h>

#define B_ 2
#define S_ 4096
#define D_ 768
#define H_ 12
#define F_ 3072
#define DK_ 64
#define QBLK 128
#define KVB 64
#define NT (S_ / KVB)

typedef __bf16 bf16x8 __attribute__((ext_vector_type(8)));
typedef float floatx4 __attribute__((ext_vector_type(4)));

__device__ __forceinline__ float bf2f(unsigned short u) {
  unsigned int x = ((unsigned int)u) << 16;
  return __builtin_bit_cast(float, x);
}
__device__ __forceinline__ unsigned short f2bf(float f) {
  unsigned int x = __builtin_bit_cast(unsigned int, f);
  x += 0x7FFFu + ((x >> 16) & 1u);
  return (unsigned short)(x >> 16);
}

// ---------------- weight transpose + cvt: w[K][N] f32 -> wt[N][K] bf16 ----------------
__global__ __launch_bounds__(256) void wtrans(const float* __restrict__ w,
                                              unsigned short* __restrict__ wt,
                                              int K, int N) {
  __shared__ float tile[32][33];
  const int n0 = blockIdx.x * 32, k0 = blockIdx.y * 32;
  const int tx = threadIdx.x & 31, ty8 = threadIdx.x >> 5;
#pragma unroll
  for (int r = 0; r < 4; r++)
    tile[ty8 + r * 8][tx] = w[(size_t)(k0 + ty8 + r * 8) * N + n0 + tx];
  __syncthreads();
#pragma unroll
  for (int r = 0; r < 4; r++)
    wt[(size_t)(n0 + ty8 + r * 8) * K + k0 + tx] = f2bf(tile[tx][ty8 + r * 8]);
}

// ---------------- GEMM: out[M][N] = A[M][K] @ Bt[N][K]^T + bias (+resid) (+relu) ----------------
template <bool A_F32, bool RELU, bool RESID, bool OUT_BF16>
__global__ __launch_bounds__(256, 2) void gemm_bt(
    const void* __restrict__ Av, const unsigned short* __restrict__ Bt,
    const float* __restrict__ bias, const float* __restrict__ resid,
    void* __restrict__ outv, int M, int N, int K) {
  __shared__ __align__(16) unsigned short As[128][40];
  __shared__ __align__(16) unsigned short Bs[128][40];
  const int t = threadIdx.x;
  const int lane = t & 63, wave = t >> 6;
  const int m0 = blockIdx.y * 128, n0 = blockIdx.x * 128;
  const int wm = (wave >> 1) * 64, wn = (wave & 1) * 64;
  const int rl = lane & 15, kl = (lane >> 4) * 8;
  const int srow = t >> 1, scol = (t & 1) * 16;

  floatx4 zf = {0.f, 0.f, 0.f, 0.f};
  floatx4 acc[4][4];
#pragma unroll
  for (int i = 0; i < 4; i++)
#pragma unroll
    for (int j = 0; j < 4; j++) acc[i][j] = zf;

  for (int k0 = 0; k0 < K; k0 += 32) {
    if (A_F32) {
      const float* ap = (const float*)Av + (size_t)(m0 + srow) * K + k0 + scol;
      float4 f[4];
#pragma unroll
      for (int q = 0; q < 4; q++) f[q] = ((const float4*)ap)[q];
      const float* fv = (const float*)&f[0];
      unsigned int w[8];
#pragma unroll
      for (int e = 0; e < 8; e++)
        w[e] = (unsigned int)f2bf(fv[2 * e]) | ((unsigned int)f2bf(fv[2 * e + 1]) << 16);
      *(uint4*)&As[srow][scol] = make_uint4(w[0], w[1], w[2], w[3]);
      *(uint4*)&As[srow][scol + 8] = make_uint4(w[4], w[5], w[6], w[7]);
    } else {
      const uint4* ap = (const uint4*)((const unsigned short*)Av + (size_t)(m0 + srow) * K + k0 + scol);
      *(uint4*)&As[srow][scol] = ap[0];
      *(uint4*)&As[srow][scol + 8] = ap[1];
    }
    {
      const uint4* bp = (const uint4*)(Bt + (size_t)(n0 + srow) * K + k0 + scol);
      *(uint4*)&Bs[srow][scol] = bp[0];
      *(uint4*)&Bs[srow][scol + 8] = bp[1];
    }
    __syncthreads();
    bf16x8 af[4], bff[4];
#pragma unroll
    for (int i = 0; i < 4; i++)
      af[i] = __builtin_bit_cast(bf16x8, *(const uint4*)&As[wm + i * 16 + rl][kl]);
#pragma unroll
    for (int j = 0; j < 4; j++)
      bff[j] = __builtin_bit_cast(bf16x8, *(const uint4*)&Bs[wn + j * 16 + rl][kl]);
#pragma unroll
    for (int i = 0; i < 4; i++)
#pragma unroll
      for (int j = 0; j < 4; j++)
        acc[i][j] = __builtin_amdgcn_mfma_f32_16x16x32_bf16(af[i], bff[j], acc[i][j], 0, 0, 0);
    __syncthreads();
  }

  const int r0 = (lane >> 4) * 4;
#pragma unroll
  for (int i = 0; i < 4; i++) {
#pragma unroll
    for (int j = 0; j < 4; j++) {
      const int col = n0 + wn + j * 16 + rl;
      const float bv = bias[col];
#pragma unroll
      for (int r = 0; r < 4; r++) {
        const int row = m0 + wm + i * 16 + r0 + r;
        float v = acc[i][j][r] + bv;
        if (RESID) v += resid[(size_t)row * N + col];
        if (RELU) v = v > 0.f ? v : 0.f;
        if (OUT_BF16)
          ((unsigned short*)outv)[(size_t)row * N + col] = f2bf(v);
        else
          ((float*)outv)[(size_t)row * N + col] = v;
      }
    }
  }
}

// ---------------- MFMA flash attention ----------------
// 256 threads = 4 waves; block handles 128 q-rows of one (b,h); wave w owns 32.
// KV tile = 64. S = Q@K^T via mfma (A=Q regs, B=Ks LDS), P via LDS round-trip,
// O += P@V via mfma (B=Vt LDS, transposed-staged).
// All LDS tiles: [R][64] u16 rows (128B), XOR-swizzled 16B chunks: chunk' = chunk ^ (row&7).
__global__ __launch_bounds__(256, 2) void flash_attn_mfma(
    const unsigned short* __restrict__ qg, const unsigned short* __restrict__ kg,
    const unsigned short* __restrict__ vg, const int* __restrict__ maskg,
    unsigned short* __restrict__ ctx) {
  __shared__ __align__(16) unsigned short Ks[64][64];      // [kv][d]
  __shared__ __align__(16) unsigned short Vt[64][64];      // [d][kv]
  __shared__ __align__(16) unsigned short Pt[4][32][64];   // per-wave [q][kv]

  const int t = threadIdx.x;
  const int lane = t & 63, wv = t >> 6;
  const int c = lane & 15, g = lane >> 4;
  const int qb = blockIdx.x, h = blockIdx.y, b = blockIdx.z;

  const size_t bS = (size_t)b * S_;
  const unsigned short* kbase = kg + bS * D_ + h * DK_;
  const unsigned short* vbase = vg + bS * D_ + h * DK_;
  const int* mp = maskg + bS;

  // Q fragments in registers: aq[i][ks], row = qb*128 + wv*32 + i*16 + c, d = ks*32 + g*8
  bf16x8 aq[2][2];
  {
    const unsigned short* qpt = qg + (bS + qb * QBLK + wv * 32) * D_ + h * DK_;
#pragma unroll
    for (int i = 0; i < 2; i++)
#pragma unroll
      for (int ks = 0; ks < 2; ks++)
        aq[i][ks] = __builtin_bit_cast(bf16x8,
            *(const uint4*)(qpt + (size_t)(i * 16 + c) * D_ + ks * 32 + g * 8));
  }

  floatx4 zf = {0.f, 0.f, 0.f, 0.f};
  floatx4 o_acc[2][4];
  float m_[8], l_[8];
#pragma unroll
  for (int i = 0; i < 2; i++)
#pragma unroll
    for (int n = 0; n < 4; n++) o_acc[i][n] = zf;
#pragma unroll
  for (int i = 0; i < 8; i++) { m_[i] = -1e30f; l_[i] = 0.f; }

  // staging: thread t covers kv row t>>2, 16-d chunks kc, kc+1
  const int skv = t >> 2;
  const int kc = (t & 3) * 2;

  uint4 kreg0, kreg1, vreg0, vreg1;
  {
    const unsigned short* kp = kbase + (size_t)skv * D_ + kc * 8;
    const unsigned short* vp = vbase + (size_t)skv * D_ + kc * 8;
    kreg0 = *(const uint4*)kp; kreg1 = *(const uint4*)(kp + 8);
    vreg0 = *(const uint4*)vp; vreg1 = *(const uint4*)(vp + 8);
  }

  for (int kt = 0; kt < NT; kt++) {
    const int kv0 = kt * KVB;
    __syncthreads();  // previous tile's LDS reads complete
    // stage K (b128, swizzled chunks)
    *(uint4*)&Ks[skv][8 * (kc ^ (skv & 7))] = kreg0;
    *(uint4*)&Ks[skv][8 * ((kc + 1) ^ (skv & 7))] = kreg1;
    // stage V transposed (b16 scatter; d&7 == e so swizzle col' = skv ^ (e<<3))
    {
      union { uint4 u; unsigned short e[8]; } u0, u1;
      u0.u = vreg0; u1.u = vreg1;
#pragma unroll
      for (int e = 0; e < 8; e++) {
        Vt[kc * 8 + e][skv ^ (e << 3)] = u0.e[e];
        Vt[kc * 8 + 8 + e][skv ^ (e << 3)] = u1.e[e];
      }
    }
    __syncthreads();  // staging visible
    // prefetch next tile (T14: latency hides under compute below)
    if (kt + 1 < NT) {
      const unsigned short* kp = kbase + (size_t)(kv0 + KVB + skv) * D_ + kc * 8;
      const unsigned short* vp = vbase + (size_t)(kv0 + KVB + skv) * D_ + kc * 8;
      kreg0 = *(const uint4*)kp; kreg1 = *(const uint4*)(kp + 8);
      vreg0 = *(const uint4*)vp; vreg1 = *(const uint4*)(vp + 8);
    }

    // ---- S = Q @ K^T. n-tile j holds kv = 4c + j (kv-interleaved N-tiling) ----
    floatx4 s_acc[2][4];
#pragma unroll
    for (int i = 0; i < 2; i++)
#pragma unroll
      for (int j = 0; j < 4; j++) s_acc[i][j] = zf;
#pragma unroll
    for (int ks = 0; ks < 2; ks++) {
      bf16x8 bk[4];
#pragma unroll
      for (int j = 0; j < 4; j++) {
        const int row = 4 * c + j;
        bk[j] = __builtin_bit_cast(bf16x8,
            *(const uint4*)&Ks[row][8 * ((ks * 4 + g) ^ (row & 7))]);
      }
#pragma unroll
      for (int i = 0; i < 2; i++)
#pragma unroll
        for (int j = 0; j < 4; j++)
          s_acc[i][j] = __builtin_amdgcn_mfma_f32_16x16x32_bf16(aq[i][ks], bk[j], s_acc[i][j], 0, 0, 0);
    }

    // ---- mask + scale (kv = 4c + j -> contiguous int4) ----
    const int4 mv = *(const int4*)&mp[kv0 + 4 * c];
    const int* mvp = (const int*)&mv;
#pragma unroll
    for (int i = 0; i < 2; i++)
#pragma unroll
      for (int j = 0; j < 4; j++) {
#pragma unroll
        for (int r = 0; r < 4; r++)
          s_acc[i][j][r] = mvp[j] ? s_acc[i][j][r] * 0.125f : -1e30f;
      }

    // ---- online softmax; row (i,r) spans j-regs x 16 lanes (c) ----
#pragma unroll
    for (int i = 0; i < 2; i++) {
#pragma unroll
      for (int r = 0; r < 4; r++) {
        const int idx = i * 4 + r;
        float rmax = fmaxf(fmaxf(s_acc[i][0][r], s_acc[i][1][r]),
                           fmaxf(s_acc[i][2][r], s_acc[i][3][r]));
#pragma unroll
        for (int off = 1; off < 16; off <<= 1) rmax = fmaxf(rmax, __shfl_xor(rmax, off, 64));
        const float mn = fmaxf(m_[idx], rmax);
        const float corr = exp2f((m_[idx] - mn) * 1.44269504088896f);
        m_[idx] = mn;
        float p[4], rs = 0.f;
#pragma unroll
        for (int j = 0; j < 4; j++) {
          p[j] = exp2f((s_acc[i][j][r] - mn) * 1.44269504088896f);
          rs += p[j];
        }
#pragma unroll
        for (int off = 1; off < 16; off <<= 1) rs += __shfl_xor(rs, off, 64);
        l_[idx] = l_[idx] * corr + rs;
#pragma unroll
        for (int n = 0; n < 4; n++) o_acc[i][n] *= corr;
        // pack 4 contiguous kv and store (b64, swizzled)
        const unsigned int w0 = (unsigned int)f2bf(p[0]) | ((unsigned int)f2bf(p[1]) << 16);
        const unsigned int w1 = (unsigned int)f2bf(p[2]) | ((unsigned int)f2bf(p[3]) << 16);
        const int q = i * 16 + g * 4 + r;
        *(uint2*)&Pt[wv][q][(4 * c) ^ ((q & 7) << 3)] = make_uint2(w0, w1);
      }
    }
    // no barrier: Pt region is per-wave, same-wave LDS RAW handled by compiler waitcnt

    // ---- O += P @ V ----
#pragma unroll
    for (int ks = 0; ks < 2; ks++) {
      bf16x8 ap[2], bvv[4];
#pragma unroll
      for (int i = 0; i < 2; i++) {
        const int row = i * 16 + c;
        ap[i] = __builtin_bit_cast(bf16x8,
            *(const uint4*)&Pt[wv][row][8 * ((ks * 4 + g) ^ (row & 7))]);
      }
#pragma unroll
      for (int n = 0; n < 4; n++) {
        const int row = n * 16 + c;
        bvv[n] = __builtin_bit_cast(bf16x8,
            *(const uint4*)&Vt[row][8 * ((ks * 4 + g) ^ (row & 7))]);
      }
#pragma unroll
      for (int i = 0; i < 2; i++)
#pragma unroll
        for (int n = 0; n < 4; n++)
          o_acc[i][n] = __builtin_amdgcn_mfma_f32_16x16x32_bf16(ap[i], bvv[n], o_acc[i][n], 0, 0, 0);
    }
  }

  // epilogue
  {
    const size_t row0 = bS + qb * QBLK + wv * 32;
#pragma unroll
    for (int i = 0; i < 2; i++) {
#pragma unroll
      for (int r = 0; r < 4; r++) {
        const float inv = 1.f / l_[i * 4 + r];
        const size_t row = row0 + i * 16 + g * 4 + r;
#pragma unroll
        for (int n = 0; n < 4; n++)
          ctx[row * D_ + h * DK_ + n * 16 + c] = f2bf(o_acc[i][n][r] * inv);
      }
    }
  }
}

// ---------------- LayerNorm over rows of 768 ----------------
__global__ __launch_bounds__(256) void ln_kernel(const float* __restrict__ x,
                                                 const float* __restrict__ g,
                                                 const float* __restrict__ be,
                                                 float* __restrict__ out) {
  __shared__ float red[4];
  const int t = threadIdx.x, lane = t & 63, wave = t >> 6;
  const size_t row = blockIdx.x;
  const float* xr = x + row * D_;
  float v0 = xr[t], v1 = xr[t + 256], v2 = xr[t + 512];
  float s = v0 + v1 + v2;
#pragma unroll
  for (int off = 32; off; off >>= 1) s += __shfl_xor(s, off, 64);
  if (lane == 0) red[wave] = s;
  __syncthreads();
  const float mu = (red[0] + red[1] + red[2] + red[3]) * (1.f / 768.f);
  __syncthreads();
  const float d0 = v0 - mu, d1 = v1 - mu, d2 = v2 - mu;
  float vs = d0 * d0 + d1 * d1 + d2 * d2;
#pragma unroll
  for (int off = 32; off; off >>= 1) vs += __shfl_xor(vs, off, 64);
  if (lane == 0) red[wave] = vs;
  __syncthreads();
  const float rs = rsqrtf((red[0] + red[1] + red[2] + red[3]) * (1.f / 768.f) + 1e-6f);
  float* orow = out + row * D_;
  orow[t] = d0 * rs * g[t] + be[t];
  orow[t + 256] = d1 * rs * g[t + 256] + be[t + 256];
  orow[t + 512] = d2 * rs * g[t + 512] + be[t + 512];
}

// ---------------- host launcher ----------------
extern "C" void kernel_launch(void* const* d_in, const int* in_sizes, int n_in,
                              void* d_out, int out_size, void* d_ws, size_t ws_size,
                              hipStream_t stream) {
  const float* xq = (const float*)d_in[0];
  const float* xk = (const float*)d_in[1];
  const float* xv = (const float*)d_in[2];
  const int* mask = (const int*)d_in[3];
  const float* wq = (const float*)d_in[4];
  const float* bq = (const float*)d_in[5];
  const float* wk = (const float*)d_in[6];
  const float* bk = (const float*)d_in[7];
  const float* wv = (const float*)d_in[8];
  const float* bv = (const float*)d_in[9];
  const float* wo = (const float*)d_in[10];
  const float* bo = (const float*)d_in[11];
  const float* w1 = (const float*)d_in[12];
  const float* b1 = (const float*)d_in[13];
  const float* w2 = (const float*)d_in[14];
  const float* b2 = (const float*)d_in[15];
  const float* g1 = (const float*)d_in[16];
  const float* be1 = (const float*)d_in[17];
  const float* g2 = (const float*)d_in[18];
  const float* be2 = (const float*)d_in[19];
  float* out = (float*)d_out;
  char* ws = (char*)d_ws;

  unsigned short* WQT = (unsigned short*)(ws + 0);
  unsigned short* WKT = (unsigned short*)(ws + 1179648);
  unsigned short* WVT = (unsigned short*)(ws + 2359296);
  unsigned short* WOT = (unsigned short*)(ws + 3538944);
  unsigned short* W1T = (unsigned short*)(ws + 4718592);
  unsigned short* W2T = (unsigned short*)(ws + 9437184);
  unsigned short* QB = (unsigned short*)(ws + 14155776);
  unsigned short* KB = (unsigned short*)(ws + 26738688);
  unsigned short* VB = (unsigned short*)(ws + 39321600);
  unsigned short* CTXB = (unsigned short*)(ws + 51904512);
  float* X1PRE = (float*)(ws + 64487424);
  float* X1F = (float*)(ws + 89653248);
  unsigned short* HB = (unsigned short*)(ws + 14155776);
  float* X2PRE = (float*)(ws + 64487424);

  wtrans<<<dim3(24, 24), 256, 0, stream>>>(wq, WQT, 768, 768);
  wtrans<<<dim3(24, 24), 256, 0, stream>>>(wk, WKT, 768, 768);
  wtrans<<<dim3(24, 24), 256, 0, stream>>>(wv, WVT, 768, 768);
  wtrans<<<dim3(24, 24), 256, 0, stream>>>(wo, WOT, 768, 768);
  wtrans<<<dim3(96, 24), 256, 0, stream>>>(w1, W1T, 768, 3072);
  wtrans<<<dim3(24, 96), 256, 0, stream>>>(w2, W2T, 3072, 768);

  gemm_bt<true, false, false, true><<<dim3(6, 64), 256, 0, stream>>>(xq, WQT, bq, nullptr, QB, 8192, 768, 768);
  gemm_bt<true, false, false, true><<<dim3(6, 64), 256, 0, stream>>>(xk, WKT, bk, nullptr, KB, 8192, 768, 768);
  gemm_bt<true, false, false, true><<<dim3(6, 64), 256, 0, stream>>>(xv, WVT, bv, nullptr, VB, 8192, 768, 768);

  flash_attn_mfma<<<dim3(S_ / QBLK, H_, B_), 256, 0, stream>>>(QB, KB, VB, mask, CTXB);

  gemm_bt<false, false, true, false><<<dim3(6, 64), 256, 0, stream>>>(CTXB, WOT, bo, xq, X1PRE, 8192, 768, 768);

  ln_kernel<<<8192, 256, 0, stream>>>(X1PRE, g1, be1, X1F);

  gemm_bt<true, true, false, true><<<dim3(24, 64), 256, 0, stream>>>(X1F, W1T, b1, nullptr, HB, 8192, 3072, 768);

  gemm_bt<false, false, true, false><<<dim3(6, 64), 256, 0, stream>>>(HB, W2T, b2, X1F, X2PRE, 8192, 768, 3072);

  ln_kernel<<<8192, 256, 0, stream>>>(X2PRE, g2, be2, out);
}

// Round 5
// 548.954 us; speedup vs baseline: 3.8078x; 1.4678x over previous
//
#include <hip/hip_runtime.h>
#include <stdint.h>

#define B_ 2
#define S_ 4096
#define D_ 768
#define H_ 12
#define F_ 3072
#define DK_ 64
#define QBLK 128
#define KVB 64
#define NT (S_ / KVB)

typedef __bf16 bf16x8 __attribute__((ext_vector_type(8)));
typedef float floatx4 __attribute__((ext_vector_type(4)));
typedef float floatx16 __attribute__((ext_vector_type(16)));

__device__ __forceinline__ float bf2f(unsigned short u) {
  unsigned int x = ((unsigned int)u) << 16;
  return __builtin_bit_cast(float, x);
}
__device__ __forceinline__ unsigned short f2bf(float f) {
  unsigned int x = __builtin_bit_cast(unsigned int, f);
  x += 0x7FFFu + ((x >> 16) & 1u);
  return (unsigned short)(x >> 16);
}
__device__ __forceinline__ unsigned int cvtpk_bf16(float lo, float hi) {
  unsigned int r;
  asm("v_cvt_pk_bf16_f32 %0, %1, %2" : "=v"(r) : "v"(lo), "v"(hi));
  return r;
}

// ---------------- weight transpose + cvt: w[K][N] f32 -> wt[N][K] bf16 ----------------
__global__ __launch_bounds__(256) void wtrans(const float* __restrict__ w,
                                              unsigned short* __restrict__ wt,
                                              int K, int N) {
  __shared__ float tile[32][33];
  const int n0 = blockIdx.x * 32, k0 = blockIdx.y * 32;
  const int tx = threadIdx.x & 31, ty8 = threadIdx.x >> 5;
#pragma unroll
  for (int r = 0; r < 4; r++)
    tile[ty8 + r * 8][tx] = w[(size_t)(k0 + ty8 + r * 8) * N + n0 + tx];
  __syncthreads();
#pragma unroll
  for (int r = 0; r < 4; r++)
    wt[(size_t)(n0 + ty8 + r * 8) * K + k0 + tx] = f2bf(tile[tx][ty8 + r * 8]);
}

// ---------------- GEMM: out[M][N] = A[M][K] @ Bt[N][K]^T + bias (+resid) (+relu) ----------------
template <bool A_F32, bool RELU, bool RESID, bool OUT_BF16>
__global__ __launch_bounds__(256, 2) void gemm_bt(
    const void* __restrict__ Av, const unsigned short* __restrict__ Bt,
    const float* __restrict__ bias, const float* __restrict__ resid,
    void* __restrict__ outv, int M, int N, int K) {
  __shared__ __align__(16) unsigned short As[128][40];
  __shared__ __align__(16) unsigned short Bs[128][40];
  const int t = threadIdx.x;
  const int lane = t & 63, wave = t >> 6;
  const int m0 = blockIdx.y * 128, n0 = blockIdx.x * 128;
  const int wm = (wave >> 1) * 64, wn = (wave & 1) * 64;
  const int rl = lane & 15, kl = (lane >> 4) * 8;
  const int srow = t >> 1, scol = (t & 1) * 16;

  floatx4 zf = {0.f, 0.f, 0.f, 0.f};
  floatx4 acc[4][4];
#pragma unroll
  for (int i = 0; i < 4; i++)
#pragma unroll
    for (int j = 0; j < 4; j++) acc[i][j] = zf;

  for (int k0 = 0; k0 < K; k0 += 32) {
    if (A_F32) {
      const float* ap = (const float*)Av + (size_t)(m0 + srow) * K + k0 + scol;
      float4 f[4];
#pragma unroll
      for (int q = 0; q < 4; q++) f[q] = ((const float4*)ap)[q];
      const float* fv = (const float*)&f[0];
      unsigned int w[8];
#pragma unroll
      for (int e = 0; e < 8; e++)
        w[e] = (unsigned int)f2bf(fv[2 * e]) | ((unsigned int)f2bf(fv[2 * e + 1]) << 16);
      *(uint4*)&As[srow][scol] = make_uint4(w[0], w[1], w[2], w[3]);
      *(uint4*)&As[srow][scol + 8] = make_uint4(w[4], w[5], w[6], w[7]);
    } else {
      const uint4* ap = (const uint4*)((const unsigned short*)Av + (size_t)(m0 + srow) * K + k0 + scol);
      *(uint4*)&As[srow][scol] = ap[0];
      *(uint4*)&As[srow][scol + 8] = ap[1];
    }
    {
      const uint4* bp = (const uint4*)(Bt + (size_t)(n0 + srow) * K + k0 + scol);
      *(uint4*)&Bs[srow][scol] = bp[0];
      *(uint4*)&Bs[srow][scol + 8] = bp[1];
    }
    __syncthreads();
    bf16x8 af[4], bff[4];
#pragma unroll
    for (int i = 0; i < 4; i++)
      af[i] = __builtin_bit_cast(bf16x8, *(const uint4*)&As[wm + i * 16 + rl][kl]);
#pragma unroll
    for (int j = 0; j < 4; j++)
      bff[j] = __builtin_bit_cast(bf16x8, *(const uint4*)&Bs[wn + j * 16 + rl][kl]);
#pragma unroll
    for (int i = 0; i < 4; i++)
#pragma unroll
      for (int j = 0; j < 4; j++)
        acc[i][j] = __builtin_amdgcn_mfma_f32_16x16x32_bf16(af[i], bff[j], acc[i][j], 0, 0, 0);
    __syncthreads();
  }

  const int r0 = (lane >> 4) * 4;
#pragma unroll
  for (int i = 0; i < 4; i++) {
#pragma unroll
    for (int j = 0; j < 4; j++) {
      const int col = n0 + wn + j * 16 + rl;
      const float bv = bias[col];
#pragma unroll
      for (int r = 0; r < 4; r++) {
        const int row = m0 + wm + i * 16 + r0 + r;
        float v = acc[i][j][r] + bv;
        if (RESID) v += resid[(size_t)row * N + col];
        if (RELU) v = v > 0.f ? v : 0.f;
        if (OUT_BF16)
          ((unsigned short*)outv)[(size_t)row * N + col] = f2bf(v);
        else
          ((float*)outv)[(size_t)row * N + col] = v;
      }
    }
  }
}

// ---------------- flash attention v3: swapped QK^T, in-register softmax (T12) ----------------
// 4 waves x 32 q rows. S^T = mfma32(K, Q): lane owns q = lane&31, 32 scores in regs.
// O^T = mfma32(V^T, P^T): P^T built in-register via cvt_pk + permlane32_swap.
// LDS: Ks[kv][d] linear b128-staged, Vt[d][kv] scatter-staged; 16B-chunk XOR swizzle (T2).
__global__ __launch_bounds__(256, 3) void flash_attn_v3(
    const unsigned short* __restrict__ qg, const unsigned short* __restrict__ kg,
    const unsigned short* __restrict__ vg, const int* __restrict__ maskg,
    unsigned short* __restrict__ ctx) {
  __shared__ __align__(16) unsigned short Ks[64][64];
  __shared__ __align__(16) unsigned short Vt[64][64];
  __shared__ float Msb[64];
  __shared__ int MsFlag;

  const int t = threadIdx.x;
  const int L = t & 63, wv = t >> 6;
  const int q5 = L & 31, h5 = L >> 5;
  const int qb = blockIdx.x, h = blockIdx.y, b = blockIdx.z;
  const size_t bS = (size_t)b * S_;
  const int hb = h * DK_;
  const unsigned short* kbase = kg + bS * D_ + hb;
  const unsigned short* vbase = vg + bS * D_ + hb;
  const int* mp = maskg + bS;

  // Q as B-fragment: lane holds Q[q = q5][d = ks*16 + h5*8 + j]
  bf16x8 bq[4];
  {
    const unsigned short* qp = qg + (bS + qb * QBLK + wv * 32 + q5) * D_ + hb + h5 * 8;
#pragma unroll
    for (int ks = 0; ks < 4; ks++)
      bq[ks] = __builtin_bit_cast(bf16x8, *(const uint4*)(qp + ks * 16));
  }

  floatx16 o0, o1;
#pragma unroll
  for (int r = 0; r < 16; r++) { o0[r] = 0.f; o1[r] = 0.f; }
  float m_ = -1e30f, l_ = 0.f;

  // staging: thread t covers kv row t>>2, 8-elem chunks kc, kc+1
  const int skv = t >> 2, kc = (t & 3) * 2;
  uint4 kr0, kr1, vr0, vr1;
  {
    const unsigned short* kp = kbase + (size_t)skv * D_ + kc * 8;
    const unsigned short* vp = vbase + (size_t)skv * D_ + kc * 8;
    kr0 = *(const uint4*)kp; kr1 = *(const uint4*)(kp + 8);
    vr0 = *(const uint4*)vp; vr1 = *(const uint4*)(vp + 8);
  }

  const int cshift = q5 & 7;

  for (int kt = 0; kt < NT; kt++) {
    const int kv0 = kt * KVB;
    __syncthreads();  // previous tile's LDS reads complete
    *(uint4*)&Ks[skv][((kc) ^ (skv & 7)) * 8] = kr0;
    *(uint4*)&Ks[skv][((kc + 1) ^ (skv & 7)) * 8] = kr1;
    {
      union { uint4 u; unsigned short e[8]; } a0, a1;
      a0.u = vr0; a1.u = vr1;
#pragma unroll
      for (int e = 0; e < 8; e++) {
        const int cp = (((skv >> 3) ^ e) << 3) | (skv & 7);
        Vt[kc * 8 + e][cp] = a0.e[e];
        Vt[kc * 8 + 8 + e][cp] = a1.e[e];
      }
    }
    if (t < 64) {
      const int mv = mp[kv0 + t];
      Msb[t] = mv ? 0.f : -1e30f;
      const unsigned long long bal = __ballot(mv != 0);
      if (t == 0) MsFlag = (bal == ~0ull) ? 1 : 0;
    }
    __syncthreads();  // staging visible
    // prefetch next tile (T14)
    if (kt + 1 < NT) {
      const unsigned short* kp = kbase + (size_t)(kv0 + KVB + skv) * D_ + kc * 8;
      const unsigned short* vp = vbase + (size_t)(kv0 + KVB + skv) * D_ + kc * 8;
      kr0 = *(const uint4*)kp; kr1 = *(const uint4*)(kp + 8);
      vr0 = *(const uint4*)vp; vr1 = *(const uint4*)(vp + 8);
    }

    // ---- S^T = K @ Q^T : s0 = kv 0-31, s1 = kv 32-63 ----
    floatx16 s0, s1;
#pragma unroll
    for (int r = 0; r < 16; r++) { s0[r] = 0.f; s1[r] = 0.f; }
    __builtin_amdgcn_s_setprio(1);
#pragma unroll
    for (int ks = 0; ks < 4; ks++) {
      bf16x8 ak0 = __builtin_bit_cast(bf16x8, *(const uint4*)&Ks[q5][(((ks << 1) | h5) ^ cshift) * 8]);
      bf16x8 ak1 = __builtin_bit_cast(bf16x8, *(const uint4*)&Ks[32 + q5][(((ks << 1) | h5) ^ cshift) * 8]);
      s0 = __builtin_amdgcn_mfma_f32_32x32x16_bf16(ak0, bq[ks], s0, 0, 0, 0);
      s1 = __builtin_amdgcn_mfma_f32_32x32x16_bf16(ak1, bq[ks], s1, 0, 0, 0);
    }
    __builtin_amdgcn_s_setprio(0);

    // ---- scale (+mask bias, slow path only) in log2 domain ----
    const float csc = 0.180336880111120419f;  // 0.125 * log2(e)
    if (MsFlag == 0) {
#pragma unroll
      for (int r = 0; r < 16; r++) {
        const int kvl = (r & 3) + 8 * (r >> 2) + 4 * h5;
        s0[r] = s0[r] * csc + Msb[kvl];
        s1[r] = s1[r] * csc + Msb[32 + kvl];
      }
    } else {
#pragma unroll
      for (int r = 0; r < 16; r++) { s0[r] *= csc; s1[r] *= csc; }
    }

    // ---- in-register row softmax (lane owns full row q) ----
    float v8[8];
#pragma unroll
    for (int i = 0; i < 8; i++)
      v8[i] = fmaxf(fmaxf(s0[i], s0[i + 8]), fmaxf(s1[i], s1[i + 8]));
    float rmax = fmaxf(fmaxf(fmaxf(v8[0], v8[4]), fmaxf(v8[1], v8[5])),
                       fmaxf(fmaxf(v8[2], v8[6]), fmaxf(v8[3], v8[7])));
    rmax = fmaxf(rmax, __shfl_xor(rmax, 32, 64));
    const float mn = fmaxf(fmaxf(m_, rmax), -1e29f);
    const float corr = exp2f(m_ - mn);
    m_ = mn;
#pragma unroll
    for (int r = 0; r < 16; r++) {
      s0[r] = exp2f(s0[r] - mn);
      s1[r] = exp2f(s1[r] - mn);
    }
    float a8[8];
#pragma unroll
    for (int i = 0; i < 8; i++) a8[i] = (s0[i] + s0[i + 8]) + (s1[i] + s1[i + 8]);
    float lsum = ((a8[0] + a8[1]) + (a8[2] + a8[3])) + ((a8[4] + a8[5]) + (a8[6] + a8[7]));
    lsum += __shfl_xor(lsum, 32, 64);
    l_ = l_ * corr + lsum;
#pragma unroll
    for (int r = 0; r < 16; r++) { o0[r] *= corr; o1[r] *= corr; }

    // ---- P^T fragments: cvt_pk pairs + permlane32_swap cross-half (T12) ----
    unsigned int w[16];
#pragma unroll
    for (int a = 0; a < 8; a++) {
      w[a] = cvtpk_bf16(s0[2 * a], s0[2 * a + 1]);
      w[8 + a] = cvtpk_bf16(s1[2 * a], s1[2 * a + 1]);
    }
#pragma unroll
    for (int ks = 0; ks < 4; ks++) {
      asm("v_permlane32_swap_b32 %0, %1" : "+v"(w[4 * ks]), "+v"(w[4 * ks + 2]));
      asm("v_permlane32_swap_b32 %0, %1" : "+v"(w[4 * ks + 1]), "+v"(w[4 * ks + 3]));
    }

    // ---- O^T += V^T @ P^T ----
    __builtin_amdgcn_s_setprio(1);
#pragma unroll
    for (int ks = 0; ks < 4; ks++) {
      const bf16x8 pa = __builtin_bit_cast(bf16x8,
          make_uint4(w[4 * ks], w[4 * ks + 1], w[4 * ks + 2], w[4 * ks + 3]));
      bf16x8 av0 = __builtin_bit_cast(bf16x8, *(const uint4*)&Vt[q5][(((ks << 1) | h5) ^ cshift) * 8]);
      bf16x8 av1 = __builtin_bit_cast(bf16x8, *(const uint4*)&Vt[32 + q5][(((ks << 1) | h5) ^ cshift) * 8]);
      o0 = __builtin_amdgcn_mfma_f32_32x32x16_bf16(av0, pa, o0, 0, 0, 0);
      o1 = __builtin_amdgcn_mfma_f32_32x32x16_bf16(av1, pa, o1, 0, 0, 0);
    }
    __builtin_amdgcn_s_setprio(0);
  }

  // ---- epilogue: normalize, pack bf16 pairs, store (lane's 32 O values = row q) ----
  {
    const float inv = 1.f / l_;
    unsigned int ep[16];
#pragma unroll
    for (int a = 0; a < 8; a++) {
      ep[a] = cvtpk_bf16(o0[2 * a] * inv, o0[2 * a + 1] * inv);
      ep[8 + a] = cvtpk_bf16(o1[2 * a] * inv, o1[2 * a + 1] * inv);
    }
    unsigned short* crow = ctx + (bS + qb * QBLK + wv * 32 + q5) * D_ + hb;
#pragma unroll
    for (int dt = 0; dt < 2; dt++)
#pragma unroll
      for (int g4 = 0; g4 < 4; g4++)
        *(uint2*)(crow + dt * 32 + g4 * 8 + h5 * 4) =
            make_uint2(ep[dt * 8 + g4 * 2], ep[dt * 8 + g4 * 2 + 1]);
  }
}

// ---------------- LayerNorm over rows of 768 ----------------
__global__ __launch_bounds__(256) void ln_kernel(const float* __restrict__ x,
                                                 const float* __restrict__ g,
                                                 const float* __restrict__ be,
                                                 float* __restrict__ out) {
  __shared__ float red[4];
  const int t = threadIdx.x, lane = t & 63, wave = t >> 6;
  const size_t row = blockIdx.x;
  const float* xr = x + row * D_;
  float v0 = xr[t], v1 = xr[t + 256], v2 = xr[t + 512];
  float s = v0 + v1 + v2;
#pragma unroll
  for (int off = 32; off; off >>= 1) s += __shfl_xor(s, off, 64);
  if (lane == 0) red[wave] = s;
  __syncthreads();
  const float mu = (red[0] + red[1] + red[2] + red[3]) * (1.f / 768.f);
  __syncthreads();
  const float d0 = v0 - mu, d1 = v1 - mu, d2 = v2 - mu;
  float vs = d0 * d0 + d1 * d1 + d2 * d2;
#pragma unroll
  for (int off = 32; off; off >>= 1) vs += __shfl_xor(vs, off, 64);
  if (lane == 0) red[wave] = vs;
  __syncthreads();
  const float rs = rsqrtf((red[0] + red[1] + red[2] + red[3]) * (1.f / 768.f) + 1e-6f);
  float* orow = out + row * D_;
  orow[t] = d0 * rs * g[t] + be[t];
  orow[t + 256] = d1 * rs * g[t + 256] + be[t + 256];
  orow[t + 512] = d2 * rs * g[t + 512] + be[t + 512];
}

// ---------------- host launcher ----------------
extern "C" void kernel_launch(void* const* d_in, const int* in_sizes, int n_in,
                              void* d_out, int out_size, void* d_ws, size_t ws_size,
                              hipStream_t stream) {
  const float* xq = (const float*)d_in[0];
  const float* xk = (const float*)d_in[1];
  const float* xv = (const float*)d_in[2];
  const int* mask = (const int*)d_in[3];
  const float* wq = (const float*)d_in[4];
  const float* bq = (const float*)d_in[5];
  const float* wk = (const float*)d_in[6];
  const float* bk = (const float*)d_in[7];
  const float* wv = (const float*)d_in[8];
  const float* bv = (const float*)d_in[9];
  const float* wo = (const float*)d_in[10];
  const float* bo = (const float*)d_in[11];
  const float* w1 = (const float*)d_in[12];
  const float* b1 = (const float*)d_in[13];
  const float* w2 = (const float*)d_in[14];
  const float* b2 = (const float*)d_in[15];
  const float* g1 = (const float*)d_in[16];
  const float* be1 = (const float*)d_in[17];
  const float* g2 = (const float*)d_in[18];
  const float* be2 = (const float*)d_in[19];
  float* out = (float*)d_out;
  char* ws = (char*)d_ws;

  unsigned short* WQT = (unsigned short*)(ws + 0);
  unsigned short* WKT = (unsigned short*)(ws + 1179648);
  unsigned short* WVT = (unsigned short*)(ws + 2359296);
  unsigned short* WOT = (unsigned short*)(ws + 3538944);
  unsigned short* W1T = (unsigned short*)(ws + 4718592);
  unsigned short* W2T = (unsigned short*)(ws + 9437184);
  unsigned short* QB = (unsigned short*)(ws + 14155776);
  unsigned short* KB = (unsigned short*)(ws + 26738688);
  unsigned short* VB = (unsigned short*)(ws + 39321600);
  unsigned short* CTXB = (unsigned short*)(ws + 51904512);
  float* X1PRE = (float*)(ws + 64487424);
  float* X1F = (float*)(ws + 89653248);
  unsigned short* HB = (unsigned short*)(ws + 14155776);
  float* X2PRE = (float*)(ws + 64487424);

  wtrans<<<dim3(24, 24), 256, 0, stream>>>(wq, WQT, 768, 768);
  wtrans<<<dim3(24, 24), 256, 0, stream>>>(wk, WKT, 768, 768);
  wtrans<<<dim3(24, 24), 256, 0, stream>>>(wv, WVT, 768, 768);
  wtrans<<<dim3(24, 24), 256, 0, stream>>>(wo, WOT, 768, 768);
  wtrans<<<dim3(96, 24), 256, 0, stream>>>(w1, W1T, 768, 3072);
  wtrans<<<dim3(24, 96), 256, 0, stream>>>(w2, W2T, 3072, 768);

  gemm_bt<true, false, false, true><<<dim3(6, 64), 256, 0, stream>>>(xq, WQT, bq, nullptr, QB, 8192, 768, 768);
  gemm_bt<true, false, false, true><<<dim3(6, 64), 256, 0, stream>>>(xk, WKT, bk, nullptr, KB, 8192, 768, 768);
  gemm_bt<true, false, false, true><<<dim3(6, 64), 256, 0, stream>>>(xv, WVT, bv, nullptr, VB, 8192, 768, 768);

  flash_attn_v3<<<dim3(S_ / QBLK, H_, B_), 256, 0, stream>>>(QB, KB, VB, mask, CTXB);

  gemm_bt<false, false, true, false><<<dim3(6, 64), 256, 0, stream>>>(CTXB, WOT, bo, xq, X1PRE, 8192, 768, 768);

  ln_kernel<<<8192, 256, 0, stream>>>(X1PRE, g1, be1, X1F);

  gemm_bt<true, true, false, true><<<dim3(24, 64), 256, 0, stream>>>(X1F, W1T, b1, nullptr, HB, 8192, 3072, 768);

  gemm_bt<false, false, true, false><<<dim3(6, 64), 256, 0, stream>>>(HB, W2T, b2, X1F, X2PRE, 8192, 768, 3072);

  ln_kernel<<<8192, 256, 0, stream>>>(X2PRE, g2, be2, out);
}

// Round 6
// 470.546 us; speedup vs baseline: 4.4423x; 1.1666x over previous
//
#include <hip/hip_runtime.h>
#include <stdint.h>

#define B_ 2
#define S_ 4096
#define D_ 768
#define H_ 12
#define F_ 3072
#define DK_ 64
#define QBLK 128
#define KVB 64
#define NT (S_ / KVB)

typedef __bf16 bf16x8 __attribute__((ext_vector_type(8)));
typedef float floatx4 __attribute__((ext_vector_type(4)));
typedef float floatx16 __attribute__((ext_vector_type(16)));

__device__ __forceinline__ float bf2f(unsigned short u) {
  unsigned int x = ((unsigned int)u) << 16;
  return __builtin_bit_cast(float, x);
}
__device__ __forceinline__ unsigned short f2bf(float f) {
  unsigned int x = __builtin_bit_cast(unsigned int, f);
  x += 0x7FFFu + ((x >> 16) & 1u);
  return (unsigned short)(x >> 16);
}
__device__ __forceinline__ unsigned int cvtpk_bf16(float lo, float hi) {
  unsigned int r;
  asm("v_cvt_pk_bf16_f32 %0, %1, %2" : "=v"(r) : "v"(lo), "v"(hi));
  return r;
}

// ---------------- weight transpose + cvt: w[K][N] f32 -> wt[N][K] bf16 ----------------
__global__ __launch_bounds__(256) void wtrans(const float* __restrict__ w,
                                              unsigned short* __restrict__ wt,
                                              int K, int N) {
  __shared__ float tile[32][33];
  const int n0 = blockIdx.x * 32, k0 = blockIdx.y * 32;
  const int tx = threadIdx.x & 31, ty8 = threadIdx.x >> 5;
#pragma unroll
  for (int r = 0; r < 4; r++)
    tile[ty8 + r * 8][tx] = w[(size_t)(k0 + ty8 + r * 8) * N + n0 + tx];
  __syncthreads();
#pragma unroll
  for (int r = 0; r < 4; r++)
    wt[(size_t)(n0 + ty8 + r * 8) * K + k0 + tx] = f2bf(tile[tx][ty8 + r * 8]);
}

// ---------------- f32 -> bf16 bulk convert (8 elems/thread) ----------------
__global__ __launch_bounds__(256) void cvt_bf16(const float* __restrict__ x,
                                                unsigned short* __restrict__ y, int n8) {
  const int i = blockIdx.x * 256 + threadIdx.x;
  if (i >= n8) return;
  const float4 a = ((const float4*)x)[2 * i];
  const float4 b = ((const float4*)x)[2 * i + 1];
  uint4 o;
  o.x = (unsigned int)f2bf(a.x) | ((unsigned int)f2bf(a.y) << 16);
  o.y = (unsigned int)f2bf(a.z) | ((unsigned int)f2bf(a.w) << 16);
  o.z = (unsigned int)f2bf(b.x) | ((unsigned int)f2bf(b.y) << 16);
  o.w = (unsigned int)f2bf(b.z) | ((unsigned int)f2bf(b.w) << 16);
  ((uint4*)y)[i] = o;
}

// ---------------- GEMM (m97 structure): out = A[M][K](bf16) @ Bt[N][K]^T + bias ----------------
// 128x128 tile, BK=32, global_load_lds width-16 staging, linear LDS, XCD swizzle.
// RESID_MODE: 0 none, 1 f32, 2 bf16.
template <bool RELU, int RESID_MODE, bool OUT_BF16>
__global__ __launch_bounds__(256, 2) void gemm_lds(
    const unsigned short* __restrict__ A, const unsigned short* __restrict__ Bt,
    const float* __restrict__ bias, const void* __restrict__ residv,
    void* __restrict__ outv, int M, int N, int K) {
  __shared__ __align__(16) unsigned short As[128 * 32];
  __shared__ __align__(16) unsigned short Bs[128 * 32];
  int bx = blockIdx.x, by = blockIdx.y;
  {
    const int gx = gridDim.x;
    const int nwg = gx * gridDim.y;       // all grids divisible by 8
    const int flat = by * gx + bx;
    const int wg = (flat & 7) * (nwg >> 3) + (flat >> 3);
    bx = wg % gx; by = wg / gx;
  }
  const int t = threadIdx.x;
  const int lane = t & 63, wave = t >> 6;
  const int m0 = by * 128, n0 = bx * 128;
  const int wm = (wave >> 1) * 64, wn = (wave & 1) * 64;
  const int rl = lane & 15, kl = (lane >> 4) * 8;
  const int srow = wave * 32 + (lane >> 2);
  const int scol = (lane & 3) * 8;

  floatx4 zf = {0.f, 0.f, 0.f, 0.f};
  floatx4 acc[4][4];
#pragma unroll
  for (int i = 0; i < 4; i++)
#pragma unroll
    for (int j = 0; j < 4; j++) acc[i][j] = zf;

  const unsigned short* Ab = A + (size_t)(m0 + srow) * K + scol;
  const unsigned short* Bb = Bt + (size_t)(n0 + srow) * K + scol;
  unsigned short* AsW = As + wave * 1024;  // wave-uniform LDS base (elements)
  unsigned short* BsW = Bs + wave * 1024;

  for (int k0 = 0; k0 < K; k0 += 32) {
    __syncthreads();  // previous tile's LDS reads done
    __builtin_amdgcn_global_load_lds(Ab + k0, AsW, 16, 0, 0);
    __builtin_amdgcn_global_load_lds(Ab + (size_t)16 * K + k0, AsW + 512, 16, 0, 0);
    __builtin_amdgcn_global_load_lds(Bb + k0, BsW, 16, 0, 0);
    __builtin_amdgcn_global_load_lds(Bb + (size_t)16 * K + k0, BsW + 512, 16, 0, 0);
    __syncthreads();  // vmcnt drained by compiler before barrier
    bf16x8 af[4], bff[4];
#pragma unroll
    for (int i = 0; i < 4; i++)
      af[i] = __builtin_bit_cast(bf16x8, *(const uint4*)&As[(wm + i * 16 + rl) * 32 + kl]);
#pragma unroll
    for (int j = 0; j < 4; j++)
      bff[j] = __builtin_bit_cast(bf16x8, *(const uint4*)&Bs[(wn + j * 16 + rl) * 32 + kl]);
#pragma unroll
    for (int i = 0; i < 4; i++)
#pragma unroll
      for (int j = 0; j < 4; j++)
        acc[i][j] = __builtin_amdgcn_mfma_f32_16x16x32_bf16(af[i], bff[j], acc[i][j], 0, 0, 0);
  }

  const int r0 = (lane >> 4) * 4;
#pragma unroll
  for (int i = 0; i < 4; i++) {
#pragma unroll
    for (int j = 0; j < 4; j++) {
      const int col = n0 + wn + j * 16 + rl;
      const float bv = bias[col];
#pragma unroll
      for (int r = 0; r < 4; r++) {
        const int row = m0 + wm + i * 16 + r0 + r;
        float v = acc[i][j][r] + bv;
        if (RESID_MODE == 1) v += ((const float*)residv)[(size_t)row * N + col];
        if (RESID_MODE == 2) v += bf2f(((const unsigned short*)residv)[(size_t)row * N + col]);
        if (RELU) v = v > 0.f ? v : 0.f;
        if (OUT_BF16)
          ((unsigned short*)outv)[(size_t)row * N + col] = f2bf(v);
        else
          ((float*)outv)[(size_t)row * N + col] = v;
      }
    }
  }
}

// ---------------- flash attention v3: swapped QK^T, in-register softmax ----------------
__global__ __launch_bounds__(256, 3) void flash_attn_v3(
    const unsigned short* __restrict__ qg, const unsigned short* __restrict__ kg,
    const unsigned short* __restrict__ vg, const int* __restrict__ maskg,
    unsigned short* __restrict__ ctx) {
  __shared__ __align__(16) unsigned short Ks[64][64];
  __shared__ __align__(16) unsigned short Vt[64][64];
  __shared__ float Msb[64];
  __shared__ int MsFlag;

  const int t = threadIdx.x;
  const int L = t & 63, wv = t >> 6;
  const int q5 = L & 31, h5 = L >> 5;
  const int qb = blockIdx.x, h = blockIdx.y, b = blockIdx.z;
  const size_t bS = (size_t)b * S_;
  const int hb = h * DK_;
  const unsigned short* kbase = kg + bS * D_ + hb;
  const unsigned short* vbase = vg + bS * D_ + hb;
  const int* mp = maskg + bS;

  bf16x8 bq[4];
  {
    const unsigned short* qp = qg + (bS + qb * QBLK + wv * 32 + q5) * D_ + hb + h5 * 8;
#pragma unroll
    for (int ks = 0; ks < 4; ks++)
      bq[ks] = __builtin_bit_cast(bf16x8, *(const uint4*)(qp + ks * 16));
  }

  floatx16 o0, o1;
#pragma unroll
  for (int r = 0; r < 16; r++) { o0[r] = 0.f; o1[r] = 0.f; }
  float m_ = -1e30f, l_ = 0.f;

  const int skv = t >> 2, kc = (t & 3) * 2;
  uint4 kr0, kr1, vr0, vr1;
  {
    const unsigned short* kp = kbase + (size_t)skv * D_ + kc * 8;
    const unsigned short* vp = vbase + (size_t)skv * D_ + kc * 8;
    kr0 = *(const uint4*)kp; kr1 = *(const uint4*)(kp + 8);
    vr0 = *(const uint4*)vp; vr1 = *(const uint4*)(vp + 8);
  }

  const int cshift = q5 & 7;
  const int vsh0 = (q5 & 7) ^ (q5 >> 3);   // Vt swizzle incl. d>>3 (bank fix)
  const int vsh1 = vsh0 ^ 4;

  for (int kt = 0; kt < NT; kt++) {
    const int kv0 = kt * KVB;
    __syncthreads();
    *(uint4*)&Ks[skv][((kc) ^ (skv & 7)) * 8] = kr0;
    *(uint4*)&Ks[skv][((kc + 1) ^ (skv & 7)) * 8] = kr1;
    {
      union { uint4 u; unsigned short e[8]; } a0, a1;
      a0.u = vr0; a1.u = vr1;
#pragma unroll
      for (int e = 0; e < 8; e++) {
        // d = kc*8+e (a0), (kc+1)*8+e (a1); f(d) = (d&7)^(d>>3) = e^kc / e^(kc+1)
        const int cp0 = (((skv >> 3) ^ e ^ kc) << 3) | (skv & 7);
        const int cp1 = (((skv >> 3) ^ e ^ (kc + 1)) << 3) | (skv & 7);
        Vt[kc * 8 + e][cp0] = a0.e[e];
        Vt[kc * 8 + 8 + e][cp1] = a1.e[e];
      }
    }
    if (t < 64) {
      const int mv = mp[kv0 + t];
      Msb[t] = mv ? 0.f : -1e30f;
      const unsigned long long bal = __ballot(mv != 0);
      if (t == 0) MsFlag = (bal == ~0ull) ? 1 : 0;
    }
    __syncthreads();
    if (kt + 1 < NT) {  // T14 prefetch
      const unsigned short* kp = kbase + (size_t)(kv0 + KVB + skv) * D_ + kc * 8;
      const unsigned short* vp = vbase + (size_t)(kv0 + KVB + skv) * D_ + kc * 8;
      kr0 = *(const uint4*)kp; kr1 = *(const uint4*)(kp + 8);
      vr0 = *(const uint4*)vp; vr1 = *(const uint4*)(vp + 8);
    }

    // ---- S^T = K @ Q^T ----
    floatx16 s0, s1;
#pragma unroll
    for (int r = 0; r < 16; r++) { s0[r] = 0.f; s1[r] = 0.f; }
    __builtin_amdgcn_s_setprio(1);
#pragma unroll
    for (int ks = 0; ks < 4; ks++) {
      bf16x8 ak0 = __builtin_bit_cast(bf16x8, *(const uint4*)&Ks[q5][(((ks << 1) | h5) ^ cshift) * 8]);
      bf16x8 ak1 = __builtin_bit_cast(bf16x8, *(const uint4*)&Ks[32 + q5][(((ks << 1) | h5) ^ cshift) * 8]);
      s0 = __builtin_amdgcn_mfma_f32_32x32x16_bf16(ak0, bq[ks], s0, 0, 0, 0);
      s1 = __builtin_amdgcn_mfma_f32_32x32x16_bf16(ak1, bq[ks], s1, 0, 0, 0);
    }
    __builtin_amdgcn_s_setprio(0);

    const float csc = 0.180336880111120419f;  // 0.125 * log2(e)
    if (MsFlag == 0) {
#pragma unroll
      for (int r = 0; r < 16; r++) {
        const int kvl = (r & 3) + 8 * (r >> 2) + 4 * h5;
        s0[r] = s0[r] * csc + Msb[kvl];
        s1[r] = s1[r] * csc + Msb[32 + kvl];
      }
    } else {
#pragma unroll
      for (int r = 0; r < 16; r++) { s0[r] *= csc; s1[r] *= csc; }
    }

    // ---- in-register row softmax + defer-max (T13, THR=8 in log2 domain) ----
    float v8[8];
#pragma unroll
    for (int i = 0; i < 8; i++)
      v8[i] = fmaxf(fmaxf(s0[i], s0[i + 8]), fmaxf(s1[i], s1[i + 8]));
    float rmax = fmaxf(fmaxf(fmaxf(v8[0], v8[4]), fmaxf(v8[1], v8[5])),
                       fmaxf(fmaxf(v8[2], v8[6]), fmaxf(v8[3], v8[7])));
    rmax = fmaxf(rmax, __shfl_xor(rmax, 32, 64));
    if (!__all(rmax <= m_ + 8.f)) {
      const float mn = fmaxf(fmaxf(m_, rmax), -1e29f);
      const float corr = exp2f(m_ - mn);
      m_ = mn;
      l_ *= corr;
#pragma unroll
      for (int r = 0; r < 16; r++) { o0[r] *= corr; o1[r] *= corr; }
    }
#pragma unroll
    for (int r = 0; r < 16; r++) {
      s0[r] = exp2f(s0[r] - m_);
      s1[r] = exp2f(s1[r] - m_);
    }
    float a8[8];
#pragma unroll
    for (int i = 0; i < 8; i++) a8[i] = (s0[i] + s0[i + 8]) + (s1[i] + s1[i + 8]);
    float lsum = ((a8[0] + a8[1]) + (a8[2] + a8[3])) + ((a8[4] + a8[5]) + (a8[6] + a8[7]));
    lsum += __shfl_xor(lsum, 32, 64);
    l_ += lsum;

    // ---- P^T fragments: cvt_pk + permlane32_swap (T12) ----
    unsigned int w[16];
#pragma unroll
    for (int a = 0; a < 8; a++) {
      w[a] = cvtpk_bf16(s0[2 * a], s0[2 * a + 1]);
      w[8 + a] = cvtpk_bf16(s1[2 * a], s1[2 * a + 1]);
    }
#pragma unroll
    for (int ks = 0; ks < 4; ks++) {
      asm("v_permlane32_swap_b32 %0, %1" : "+v"(w[4 * ks]), "+v"(w[4 * ks + 2]));
      asm("v_permlane32_swap_b32 %0, %1" : "+v"(w[4 * ks + 1]), "+v"(w[4 * ks + 3]));
    }

    // ---- O^T += V^T @ P^T ----
    __builtin_amdgcn_s_setprio(1);
#pragma unroll
    for (int ks = 0; ks < 4; ks++) {
      const bf16x8 pa = __builtin_bit_cast(bf16x8,
          make_uint4(w[4 * ks], w[4 * ks + 1], w[4 * ks + 2], w[4 * ks + 3]));
      bf16x8 av0 = __builtin_bit_cast(bf16x8, *(const uint4*)&Vt[q5][(((ks << 1) | h5) ^ vsh0) * 8]);
      bf16x8 av1 = __builtin_bit_cast(bf16x8, *(const uint4*)&Vt[32 + q5][(((ks << 1) | h5) ^ vsh1) * 8]);
      o0 = __builtin_amdgcn_mfma_f32_32x32x16_bf16(av0, pa, o0, 0, 0, 0);
      o1 = __builtin_amdgcn_mfma_f32_32x32x16_bf16(av1, pa, o1, 0, 0, 0);
    }
    __builtin_amdgcn_s_setprio(0);
  }

  {
    const float inv = 1.f / l_;
    unsigned int ep[16];
#pragma unroll
    for (int a = 0; a < 8; a++) {
      ep[a] = cvtpk_bf16(o0[2 * a] * inv, o0[2 * a + 1] * inv);
      ep[8 + a] = cvtpk_bf16(o1[2 * a] * inv, o1[2 * a + 1] * inv);
    }
    unsigned short* crow = ctx + (bS + qb * QBLK + wv * 32 + q5) * D_ + hb;
#pragma unroll
    for (int dt = 0; dt < 2; dt++)
#pragma unroll
      for (int g4 = 0; g4 < 4; g4++)
        *(uint2*)(crow + dt * 32 + g4 * 8 + h5 * 4) =
            make_uint2(ep[dt * 8 + g4 * 2], ep[dt * 8 + g4 * 2 + 1]);
  }
}

// ---------------- LayerNorm over rows of 768 ----------------
template <bool OUT_BF16>
__global__ __launch_bounds__(256) void ln_kernel(const float* __restrict__ x,
                                                 const float* __restrict__ g,
                                                 const float* __restrict__ be,
                                                 void* __restrict__ outv) {
  __shared__ float red[4];
  const int t = threadIdx.x, lane = t & 63, wave = t >> 6;
  const size_t row = blockIdx.x;
  const float* xr = x + row * D_;
  float v0 = xr[t], v1 = xr[t + 256], v2 = xr[t + 512];
  float s = v0 + v1 + v2;
#pragma unroll
  for (int off = 32; off; off >>= 1) s += __shfl_xor(s, off, 64);
  if (lane == 0) red[wave] = s;
  __syncthreads();
  const float mu = (red[0] + red[1] + red[2] + red[3]) * (1.f / 768.f);
  __syncthreads();
  const float d0 = v0 - mu, d1 = v1 - mu, d2 = v2 - mu;
  float vs = d0 * d0 + d1 * d1 + d2 * d2;
#pragma unroll
  for (int off = 32; off; off >>= 1) vs += __shfl_xor(vs, off, 64);
  if (lane == 0) red[wave] = vs;
  __syncthreads();
  const float rs = rsqrtf((red[0] + red[1] + red[2] + red[3]) * (1.f / 768.f) + 1e-6f);
  const float r0v = d0 * rs * g[t] + be[t];
  const float r1v = d1 * rs * g[t + 256] + be[t + 256];
  const float r2v = d2 * rs * g[t + 512] + be[t + 512];
  if (OUT_BF16) {
    unsigned short* o = (unsigned short*)outv + row * D_;
    o[t] = f2bf(r0v); o[t + 256] = f2bf(r1v); o[t + 512] = f2bf(r2v);
  } else {
    float* o = (float*)outv + row * D_;
    o[t] = r0v; o[t + 256] = r1v; o[t + 512] = r2v;
  }
}

// ---------------- host launcher ----------------
extern "C" void kernel_launch(void* const* d_in, const int* in_sizes, int n_in,
                              void* d_out, int out_size, void* d_ws, size_t ws_size,
                              hipStream_t stream) {
  const float* xq = (const float*)d_in[0];
  const float* xk = (const float*)d_in[1];
  const float* xv = (const float*)d_in[2];
  const int* mask = (const int*)d_in[3];
  const float* wq = (const float*)d_in[4];
  const float* bq = (const float*)d_in[5];
  const float* wk = (const float*)d_in[6];
  const float* bk = (const float*)d_in[7];
  const float* wv = (const float*)d_in[8];
  const float* bv = (const float*)d_in[9];
  const float* wo = (const float*)d_in[10];
  const float* bo = (const float*)d_in[11];
  const float* w1 = (const float*)d_in[12];
  const float* b1 = (const float*)d_in[13];
  const float* w2 = (const float*)d_in[14];
  const float* b2 = (const float*)d_in[15];
  const float* g1 = (const float*)d_in[16];
  const float* be1 = (const float*)d_in[17];
  const float* g2 = (const float*)d_in[18];
  const float* be2 = (const float*)d_in[19];
  float* out = (float*)d_out;
  char* ws = (char*)d_ws;

  // workspace layout (bytes); high water 114819072 (= previous known-safe max)
  unsigned short* WQT = (unsigned short*)(ws + 0);
  unsigned short* WKT = (unsigned short*)(ws + 1179648);
  unsigned short* WVT = (unsigned short*)(ws + 2359296);
  unsigned short* WOT = (unsigned short*)(ws + 3538944);
  unsigned short* W1T = (unsigned short*)(ws + 4718592);
  unsigned short* W2T = (unsigned short*)(ws + 9437184);
  unsigned short* XQB = (unsigned short*)(ws + 14155776);   // 12.58MB each
  unsigned short* XKB = (unsigned short*)(ws + 26738688);
  unsigned short* XVB = (unsigned short*)(ws + 39321600);
  unsigned short* QB = (unsigned short*)(ws + 51904512);
  unsigned short* KB = (unsigned short*)(ws + 64487424);
  unsigned short* VB = (unsigned short*)(ws + 77070336);
  unsigned short* CTXB = (unsigned short*)(ws + 14155776);  // alias XQB (dead post-QKV)
  float* X1PRE = (float*)(ws + 51904512);                   // alias QB+KB (dead post-flash)
  unsigned short* X1B = (unsigned short*)(ws + 77070336);   // alias VB (dead post-flash)
  unsigned short* HB = (unsigned short*)(ws + 14155776);    // alias CTXB..X1PRE-half (dead)
  float* X2PRE = (float*)(ws + 89653248);                   // fresh region, ends 114819072

  wtrans<<<dim3(24, 24), 256, 0, stream>>>(wq, WQT, 768, 768);
  wtrans<<<dim3(24, 24), 256, 0, stream>>>(wk, WKT, 768, 768);
  wtrans<<<dim3(24, 24), 256, 0, stream>>>(wv, WVT, 768, 768);
  wtrans<<<dim3(24, 24), 256, 0, stream>>>(wo, WOT, 768, 768);
  wtrans<<<dim3(96, 24), 256, 0, stream>>>(w1, W1T, 768, 3072);
  wtrans<<<dim3(24, 96), 256, 0, stream>>>(w2, W2T, 3072, 768);

  cvt_bf16<<<3072, 256, 0, stream>>>(xq, XQB, 786432);
  cvt_bf16<<<3072, 256, 0, stream>>>(xk, XKB, 786432);
  cvt_bf16<<<3072, 256, 0, stream>>>(xv, XVB, 786432);

  gemm_lds<false, 0, true><<<dim3(6, 64), 256, 0, stream>>>(XQB, WQT, bq, nullptr, QB, 8192, 768, 768);
  gemm_lds<false, 0, true><<<dim3(6, 64), 256, 0, stream>>>(XKB, WKT, bk, nullptr, KB, 8192, 768, 768);
  gemm_lds<false, 0, true><<<dim3(6, 64), 256, 0, stream>>>(XVB, WVT, bv, nullptr, VB, 8192, 768, 768);

  flash_attn_v3<<<dim3(S_ / QBLK, H_, B_), 256, 0, stream>>>(QB, KB, VB, mask, CTXB);

  gemm_lds<false, 1, false><<<dim3(6, 64), 256, 0, stream>>>(CTXB, WOT, bo, xq, X1PRE, 8192, 768, 768);

  ln_kernel<true><<<8192, 256, 0, stream>>>(X1PRE, g1, be1, X1B);

  gemm_lds<true, 0, true><<<dim3(24, 64), 256, 0, stream>>>(X1B, W1T, b1, nullptr, HB, 8192, 3072, 768);

  gemm_lds<false, 2, false><<<dim3(6, 64), 256, 0, stream>>>(HB, W2T, b2, X1B, X2PRE, 8192, 768, 3072);

  ln_kernel<false><<<8192, 256, 0, stream>>>(X2PRE, g2, be2, out);
}